// Round 1
// baseline (933.449 us; speedup 1.0000x reference)
//
#include <hip/hip_runtime.h>
#include <hip/hip_bf16.h>
#include <stdint.h>

#define T_TOKENS 2048
#define HID_DIM 1024
#define INTER 3584
#define NEXP 8

typedef float f32x4 __attribute__((ext_vector_type(4)));
typedef short short8 __attribute__((ext_vector_type(8)));
typedef unsigned short ushort8 __attribute__((ext_vector_type(8)));

#define AS1 __attribute__((address_space(1)))
#define AS3 __attribute__((address_space(3)))

__device__ __forceinline__ void gload_lds16(const void* g, void* l) {
    __builtin_amdgcn_global_load_lds((AS1 void*)g, (AS3 void*)l, 16, 0, 0);
}

__device__ __forceinline__ f32x4 mfma16(short8 a, short8 b, f32x4 c) {
    return __builtin_amdgcn_mfma_f32_16x16x32_bf16(a, b, c, 0, 0, 0);
}

__device__ __forceinline__ unsigned short f2bf(float f) {
    union { __hip_bfloat16 h; unsigned short u; } cv;
    cv.h = __float2bfloat16(f);
    return cv.u;
}

__device__ __forceinline__ ushort8 cvt8(float4 v0, float4 v1) {
    ushort8 u;
    u[0] = f2bf(v0.x); u[1] = f2bf(v0.y); u[2] = f2bf(v0.z); u[3] = f2bf(v0.w);
    u[4] = f2bf(v1.x); u[5] = f2bf(v1.y); u[6] = f2bf(v1.z); u[7] = f2bf(v1.w);
    return u;
}

// ---------------- router: logits (fp32 exact), top-2, counts; X -> bf16 ----------------
__global__ void router_k(const float* __restrict__ x, const float* __restrict__ gw,
                         unsigned short* __restrict__ xb,
                         int* __restrict__ topk_e, float* __restrict__ topk_w,
                         int* __restrict__ ctl) {
    int lane = threadIdx.x & 63;
    int wid = threadIdx.x >> 6;
    int t = blockIdx.x * 4 + wid;
    const float* xr = x + (size_t)t * HID_DIM;

    float acc[NEXP];
#pragma unroll
    for (int e = 0; e < NEXP; ++e) acc[e] = 0.f;

#pragma unroll
    for (int j = 0; j < 4; ++j) {
        int c = j * 256 + lane * 4;
        float4 v = *reinterpret_cast<const float4*>(xr + c);
        ushort4 b;
        b.x = f2bf(v.x); b.y = f2bf(v.y); b.z = f2bf(v.z); b.w = f2bf(v.w);
        *reinterpret_cast<ushort4*>(xb + (size_t)t * HID_DIM + c) = b;
#pragma unroll
        for (int e = 0; e < NEXP; ++e) {
            float4 g = *reinterpret_cast<const float4*>(gw + e * HID_DIM + c);
            acc[e] += v.x * g.x + v.y * g.y + v.z * g.z + v.w * g.w;
        }
    }
#pragma unroll
    for (int off = 32; off > 0; off >>= 1)
#pragma unroll
        for (int e = 0; e < NEXP; ++e) acc[e] += __shfl_xor(acc[e], off, 64);

    if (lane == 0) {
        int e0 = 0;
#pragma unroll
        for (int e = 1; e < NEXP; ++e) if (acc[e] > acc[e0]) e0 = e;
        int e1 = -1;
        float b1 = 0.f;
#pragma unroll
        for (int e = 0; e < NEXP; ++e) {
            if (e == e0) continue;
            if (e1 < 0 || acc[e] > b1) { e1 = e; b1 = acc[e]; }
        }
        float p1 = __expf(b1 - acc[e0]);   // renormalized top-2: softmax denom cancels
        float s = 1.f + p1;
        topk_e[2 * t] = e0; topk_e[2 * t + 1] = e1;
        topk_w[2 * t] = 1.f / s; topk_w[2 * t + 1] = p1 / s;
        atomicAdd(&ctl[e0], 1);
        atomicAdd(&ctl[e1], 1);
    }
}

// ctl layout (ints): [0..8) counts, [16..24) cursors, [32..40) offsets
__global__ void prefix_k(int* __restrict__ ctl) {
    if (threadIdx.x == 0) {
        int r = 0;
        for (int e = 0; e < NEXP; ++e) {
            ctl[32 + e] = r;
            r += ctl[e];
            ctl[16 + e] = 0;
        }
    }
}

__global__ void scatter_k(const int* __restrict__ topk_e, const float* __restrict__ topk_w,
                          int* __restrict__ ctl, int* __restrict__ perm_token,
                          float* __restrict__ perm_gate) {
    int t = blockIdx.x * 256 + threadIdx.x;
    if (t >= T_TOKENS) return;
#pragma unroll
    for (int k = 0; k < 2; ++k) {
        int e = topk_e[2 * t + k];
        int p = ctl[32 + e] + atomicAdd(&ctl[16 + e], 1);
        perm_token[p] = t;
        perm_gate[p] = topk_w[2 * t + k];
    }
}

// ---------------- GEMM1: hid = silu(Xg @ w1^T) * (Xg @ w3^T), gathered rows ----------------
// tile: BM=128 rows, BN=64 cols (per matrix), BK=32. 4 waves (2x2), wave = 64 rows x 32 cols.
__global__ __launch_bounds__(256) void gemm1_k(
    const unsigned short* __restrict__ xb,
    const float* __restrict__ w1, const float* __restrict__ w3,
    const int* __restrict__ ctl, const int* __restrict__ perm_token,
    unsigned short* __restrict__ hid) {
    int e = blockIdx.z;
    int cnt = ctl[e];
    int tm = blockIdx.x;
    if (tm * 128 >= cnt) return;
    int off = ctl[32 + e];
    int cb = blockIdx.y * 64;

    __shared__ __attribute__((aligned(16))) unsigned short A_l[512 * 8];  // [kb][row][8]
    __shared__ __attribute__((aligned(16))) unsigned short B1_l[256 * 8]; // [kb][col][8]
    __shared__ __attribute__((aligned(16))) unsigned short B3_l[256 * 8];

    int tid = threadIdx.x;
    int lane = tid & 63;
    int wid = tid >> 6;
    int wr = wid >> 1, wc = wid & 1;

    // A staging: thread stages row (tid&127), kb = (tid>>7) + 2*round
    int arow = tid & 127;
    int grow = tm * 128 + arow;
    int tok = (grow < cnt) ? perm_token[off + grow] : 0;
    const unsigned short* asrc = xb + (size_t)tok * HID_DIM;
    int kb0 = tid >> 7;
    unsigned short* adst0 = A_l + (size_t)(wid * 64) * 8;        // wave-uniform
    unsigned short* adst1 = A_l + (size_t)(256 + wid * 64) * 8;

    // B staging: thread -> (col = tid>>2, kb = tid&3), 8 consecutive k
    int bcol = tid >> 2;
    int bkb = tid & 3;
    const float* b1src = w1 + ((size_t)e * INTER + cb + bcol) * HID_DIM + bkb * 8;
    const float* b3src = w3 + ((size_t)e * INTER + cb + bcol) * HID_DIM + bkb * 8;
    unsigned short* b1dst = B1_l + (size_t)(bkb * 64 + bcol) * 8;
    unsigned short* b3dst = B3_l + (size_t)(bkb * 64 + bcol) * 8;

    f32x4 acc1[4][2], acc3[4][2];
#pragma unroll
    for (int i = 0; i < 4; ++i)
#pragma unroll
        for (int j = 0; j < 2; ++j) { acc1[i][j] = 0.f; acc3[i][j] = 0.f; }

    const unsigned short* a_rd = A_l + (size_t)(((lane >> 4) * 128) + wr * 64 + (lane & 15)) * 8;
    const unsigned short* b1_rd = B1_l + (size_t)(((lane >> 4) * 64) + wc * 32 + (lane & 15)) * 8;
    const unsigned short* b3_rd = B3_l + (size_t)(((lane >> 4) * 64) + wc * 32 + (lane & 15)) * 8;

    for (int k0 = 0; k0 < HID_DIM; k0 += 32) {
        gload_lds16(asrc + k0 + kb0 * 8, adst0);
        gload_lds16(asrc + k0 + (kb0 + 2) * 8, adst1);
        {
            float4 v0 = *reinterpret_cast<const float4*>(b1src + k0);
            float4 v1 = *reinterpret_cast<const float4*>(b1src + k0 + 4);
            *reinterpret_cast<ushort8*>(b1dst) = cvt8(v0, v1);
            float4 u0 = *reinterpret_cast<const float4*>(b3src + k0);
            float4 u1 = *reinterpret_cast<const float4*>(b3src + k0 + 4);
            *reinterpret_cast<ushort8*>(b3dst) = cvt8(u0, u1);
        }
        __syncthreads();
        short8 a[4], bf1[2], bf3[2];
#pragma unroll
        for (int i = 0; i < 4; ++i)
            a[i] = *reinterpret_cast<const short8*>(a_rd + i * 128);
#pragma unroll
        for (int j = 0; j < 2; ++j) {
            bf1[j] = *reinterpret_cast<const short8*>(b1_rd + j * 128);
            bf3[j] = *reinterpret_cast<const short8*>(b3_rd + j * 128);
        }
#pragma unroll
        for (int i = 0; i < 4; ++i)
#pragma unroll
            for (int j = 0; j < 2; ++j) {
                acc1[i][j] = mfma16(a[i], bf1[j], acc1[i][j]);
                acc3[i][j] = mfma16(a[i], bf3[j], acc3[i][j]);
            }
        __syncthreads();
    }

    // epilogue: silu(g) * u -> bf16 hid rows (permuted order)
    int rbase = tm * 128 + wr * 64 + ((lane >> 4) * 4);
    int fbase = cb + wc * 32 + (lane & 15);
#pragma unroll
    for (int i = 0; i < 4; ++i) {
#pragma unroll
        for (int r = 0; r < 4; ++r) {
            int grow2 = rbase + i * 16 + r;
            if (grow2 < cnt) {
                size_t hrow = (size_t)(off + grow2) * INTER;
#pragma unroll
                for (int j = 0; j < 2; ++j) {
                    float g = acc1[i][j][r];
                    float u = acc3[i][j][r];
                    float h = (g / (1.f + __expf(-g))) * u;
                    hid[hrow + fbase + j * 16] = f2bf(h);
                }
            }
        }
    }
}

// ---------------- GEMM2: out[tok] += gate * (hid @ w2^T), BM=128 BN=128 BK=32 ----------------
__global__ __launch_bounds__(256) void gemm2_k(
    const unsigned short* __restrict__ hid, const float* __restrict__ w2,
    const int* __restrict__ ctl, const int* __restrict__ perm_token,
    const float* __restrict__ perm_gate, float* __restrict__ out) {
    int e = blockIdx.z;
    int cnt = ctl[e];
    int tm = blockIdx.x;
    if (tm * 128 >= cnt) return;
    int off = ctl[32 + e];
    int cb = blockIdx.y * 128;

    __shared__ __attribute__((aligned(16))) unsigned short A_l[512 * 8]; // [kb][row][8]
    __shared__ __attribute__((aligned(16))) unsigned short B_l[512 * 8]; // [kb][col][8]

    int tid = threadIdx.x;
    int lane = tid & 63;
    int wid = tid >> 6;
    int wr = wid >> 1, wc = wid & 1;

    int arow = tid & 127;
    int ap = off + tm * 128 + arow;
    if (ap > T_TOKENS * 2 - 1) ap = T_TOKENS * 2 - 1;  // clamp; garbage rows discarded
    const unsigned short* asrc = hid + (size_t)ap * INTER;
    int kb0 = tid >> 7;
    unsigned short* adst0 = A_l + (size_t)(wid * 64) * 8;
    unsigned short* adst1 = A_l + (size_t)(256 + wid * 64) * 8;

    const float* w2e = w2 + (size_t)e * HID_DIM * INTER;
    int bcol = tid >> 2;
    int bkb = tid & 3;
    const float* bsrc0 = w2e + (size_t)(cb + bcol) * INTER + bkb * 8;
    const float* bsrc1 = bsrc0 + (size_t)64 * INTER;
    unsigned short* bdst0 = B_l + (size_t)(bkb * 128 + bcol) * 8;
    unsigned short* bdst1 = bdst0 + 64 * 8;

    f32x4 acc[4][4];
#pragma unroll
    for (int i = 0; i < 4; ++i)
#pragma unroll
        for (int j = 0; j < 4; ++j) acc[i][j] = 0.f;

    const unsigned short* a_rd = A_l + (size_t)(((lane >> 4) * 128) + wr * 64 + (lane & 15)) * 8;
    const unsigned short* b_rd = B_l + (size_t)(((lane >> 4) * 128) + wc * 64 + (lane & 15)) * 8;

    for (int k0 = 0; k0 < INTER; k0 += 32) {
        gload_lds16(asrc + k0 + kb0 * 8, adst0);
        gload_lds16(asrc + k0 + (kb0 + 2) * 8, adst1);
        {
            float4 v0 = *reinterpret_cast<const float4*>(bsrc0 + k0);
            float4 v1 = *reinterpret_cast<const float4*>(bsrc0 + k0 + 4);
            *reinterpret_cast<ushort8*>(bdst0) = cvt8(v0, v1);
            float4 u0 = *reinterpret_cast<const float4*>(bsrc1 + k0);
            float4 u1 = *reinterpret_cast<const float4*>(bsrc1 + k0 + 4);
            *reinterpret_cast<ushort8*>(bdst1) = cvt8(u0, u1);
        }
        __syncthreads();
        short8 a[4], b[4];
#pragma unroll
        for (int i = 0; i < 4; ++i) a[i] = *reinterpret_cast<const short8*>(a_rd + i * 128);
#pragma unroll
        for (int j = 0; j < 4; ++j) b[j] = *reinterpret_cast<const short8*>(b_rd + j * 128);
#pragma unroll
        for (int i = 0; i < 4; ++i)
#pragma unroll
            for (int j = 0; j < 4; ++j) acc[i][j] = mfma16(a[i], b[j], acc[i][j]);
        __syncthreads();
    }

    int rb = wr * 64 + ((lane >> 4) * 4);
    int hb = cb + wc * 64 + (lane & 15);
#pragma unroll
    for (int i = 0; i < 4; ++i) {
#pragma unroll
        for (int r = 0; r < 4; ++r) {
            int lrow = rb + i * 16 + r;
            int grow = tm * 128 + lrow;
            if (grow < cnt) {
                int p = off + grow;
                int tok = perm_token[p];
                float gate = perm_gate[p];
#pragma unroll
                for (int j = 0; j < 4; ++j)
                    atomicAdd(&out[(size_t)tok * HID_DIM + hb + j * 16], acc[i][j][r] * gate);
            }
        }
    }
}

extern "C" void kernel_launch(void* const* d_in, const int* in_sizes, int n_in,
                              void* d_out, int out_size, void* d_ws, size_t ws_size,
                              hipStream_t stream) {
    const float* x  = (const float*)d_in[0];
    const float* gw = (const float*)d_in[1];
    const float* w1 = (const float*)d_in[2];
    const float* w2 = (const float*)d_in[3];
    const float* w3 = (const float*)d_in[4];
    float* out = (float*)d_out;

    char* ws = (char*)d_ws;
    int*   ctl        = (int*)ws;                              // 256 B control
    int*   topk_e     = (int*)(ws + 1024);                     // 16 KB
    float* topk_w     = (float*)(ws + 1024 + 16384);           // 16 KB
    int*   perm_token = (int*)(ws + 1024 + 2 * 16384);         // 16 KB
    float* perm_gate  = (float*)(ws + 1024 + 3 * 16384);       // 16 KB
    unsigned short* xb  = (unsigned short*)(ws + 1024 + 4 * 16384);                   // 4 MB
    unsigned short* hid = (unsigned short*)(ws + 1024 + 4 * 16384 + (size_t)T_TOKENS * HID_DIM * 2); // 28.7 MB

    hipMemsetAsync(ctl, 0, 256, stream);
    hipMemsetAsync(out, 0, (size_t)out_size * sizeof(float), stream);

    router_k<<<dim3(T_TOKENS / 4), 256, 0, stream>>>(x, gw, xb, topk_e, topk_w, ctl);
    prefix_k<<<dim3(1), 64, 0, stream>>>(ctl);
    scatter_k<<<dim3(T_TOKENS / 256), 256, 0, stream>>>(topk_e, topk_w, ctl, perm_token, perm_gate);
    gemm1_k<<<dim3(16, INTER / 64, NEXP), 256, 0, stream>>>(xb, w1, w3, ctl, perm_token, hid);
    gemm2_k<<<dim3(16, HID_DIM / 128, NEXP), 256, 0, stream>>>(hid, w2, ctl, perm_token, perm_gate, out);
}